// Round 11
// baseline (101.539 us; speedup 1.0000x reference)
//
#include <hip/hip_runtime.h>
#include <cstddef>

// MPS classifier: SIZE=784, D=32, DLOC=2, NUM_LABELS=10, LABEL_SITE=392, B=128
//
// Round-11: r9 site loop (best: 93.2us) + double TLP, halve serial chain.
//  - r10's E0/D split (16 chained MFMAs/site) REGRESSED -> kchain is
//    dependent-latency-bound, not VALU-bound. So: 32 segments/chain (13/12
//    sites each), 1024 blocks x 512 thr = 32 waves/CU (8/SIMD, double r9),
//    per-wave serial chain 25 -> 13 sites. launch_bounds(512,8).
//  - XCD swizzle: bid&7 = hside*4+quarter -> the 128 blocks sharing a site
//    range land on one XCD (400KB slice resident in its L2).
//  - Site update = r9's verified blend (unpack shl/and + fma + pack, 8 MFMA).
//  - In-block 3-level T-world tree fold unchanged (verified r9 layout math).
//  - gfin: 8 fold_steps (quarters ascending: R0..R3 then L0..L3), H =
//    Left^T*Right^T, label contraction.
// ws: [core2b 3.2MB][halfbuf 1024*1024 f = 4MB].

typedef short bfrag __attribute__((ext_vector_type(4)));   // 4 bf16
typedef float facc  __attribute__((ext_vector_type(4)));   // 4 fp32

#if !defined(__HIP_DEVICE_COMPILE__)
#define MFMA16(a, b, c) (c)  // host-pass stub (host clang lacks amdgcn builtins)
#elif __has_builtin(__builtin_amdgcn_mfma_f32_16x16x16bf16_1k)
#define MFMA16(a, b, c) __builtin_amdgcn_mfma_f32_16x16x16bf16_1k(a, b, c, 0, 0, 0)
#elif __has_builtin(__builtin_amdgcn_mfma_f32_16x16x16_bf16)
#define MFMA16(a, b, c) __builtin_amdgcn_mfma_f32_16x16x16_bf16(a, b, c, 0, 0, 0)
#else
#error "no 16x16x16 bf16 MFMA builtin on this target"
#endif

#define CORE2B_DWORDS (784 * 1024)

__device__ __forceinline__ short bf16h(float v) {
  unsigned u = __float_as_uint(v) + 0x8000u;  // round-half-up to bf16
  return (short)(u >> 16);
}

// pack 4 fp32 -> 4 bf16 (HW cvt_pk on gfx950, manual fallback)
#if defined(__HIP_DEVICE_COMPILE__) && __has_builtin(__builtin_amdgcn_cvt_pk_bf16_f32)
typedef __bf16 bf16x2 __attribute__((ext_vector_type(2)));
__device__ __forceinline__ bfrag packf4(float a, float b, float c, float d) {
  bf16x2 lo = __builtin_amdgcn_cvt_pk_bf16_f32(a, b);
  bf16x2 hi = __builtin_amdgcn_cvt_pk_bf16_f32(c, d);
  uint2 u = make_uint2(__builtin_bit_cast(unsigned, lo), __builtin_bit_cast(unsigned, hi));
  return __builtin_bit_cast(bfrag, u);
}
#else
__device__ __forceinline__ bfrag packf4(float a, float b, float c, float d) {
  bfrag r; r[0] = bf16h(a); r[1] = bf16h(b); r[2] = bf16h(c); r[3] = bf16h(d);
  return r;
}
#endif

__device__ __forceinline__ bfrag pack4(const facc v) {
  return packf4(v[0], v[1], v[2], v[3]);
}

// fp32 -> (hi bf16 rounded, lo bf16 of remainder) — cold path (folds only)
__device__ __forceinline__ void split4(const float* v, bfrag& hi, bfrag& lo) {
#pragma unroll
  for (int j = 0; j < 4; ++j) {
    unsigned u = (__float_as_uint(v[j]) + 0x8000u) & 0xFFFF0000u;
    hi[j] = (short)(u >> 16);
    float lf = v[j] - __uint_as_float(u);
    lo[j] = bf16h(lf);
  }
}

// One fold step: acc <- A * acc (3-term bf16 hi/lo split).
// av[R][H] = float4 A-frag: A[16R+col16][16H+4q .. +3].
__device__ __forceinline__ void fold_step(facc (&acc)[2][2], const float4 (&av)[2][2]) {
  bfrag Ahi[2][2], Alo[2][2], Bhi[2][2], Blo[2][2];
#pragma unroll
  for (int R = 0; R < 2; ++R)
#pragma unroll
    for (int H = 0; H < 2; ++H) {
      float v[4] = {av[R][H].x, av[R][H].y, av[R][H].z, av[R][H].w};
      split4(v, Ahi[R][H], Alo[R][H]);
    }
#pragma unroll
  for (int H = 0; H < 2; ++H)
#pragma unroll
    for (int c = 0; c < 2; ++c) {
      float v[4] = {acc[H][c][0], acc[H][c][1], acc[H][c][2], acc[H][c][3]};
      split4(v, Bhi[H][c], Blo[H][c]);
    }
  facc n[2][2];
#pragma unroll
  for (int R = 0; R < 2; ++R)
#pragma unroll
    for (int c = 0; c < 2; ++c) {
      facc z;
#pragma unroll
      for (int j = 0; j < 4; ++j) z[j] = 0.0f;
#pragma unroll
      for (int H = 0; H < 2; ++H) {
        z = MFMA16(Ahi[R][H], Bhi[H][c], z);
        z = MFMA16(Ahi[R][H], Blo[H][c], z);
        z = MFMA16(Alo[R][H], Bhi[H][c], z);
      }
      n[R][c] = z;
    }
#pragma unroll
  for (int R = 0; R < 2; ++R)
#pragma unroll
    for (int c = 0; c < 2; ++c) acc[R][c] = n[R][c];
}

// ---------------------------------------------------------------------------
// K0: core -> core2b (r9 layout). Coalesced reads, scattered 8B writes.
// dest dword idx = ((r*2+h2)*64 + 16q+col16)*4 + j, value (bf16(d)<<16)|bf16(e0).
// ---------------------------------------------------------------------------
__global__ __launch_bounds__(256) void xform_k(const float* __restrict__ core,
                                               unsigned* __restrict__ core2b) {
  const int s = blockIdx.x;  // 0..783
  const int tid = threadIdx.x;
  const float4* src = (const float4*)(core + (size_t)s * 2048);
  unsigned* dst = core2b + (size_t)s * 1024;
#pragma unroll
  for (int u = 0; u < 2; ++u) {
    int v = tid + 256 * u;  // 0..511, coalesced
    float4 f = src[v];
    int i = v >> 4;
    int c = (v & 15) * 2;
    int r = i >> 4, col16 = i & 15;
    int h2 = c >> 4, cl = c & 15;
    int q = cl >> 2, j = cl & 3;  // j in {0,2}
    float e0a = f.x - ((i == c) ? 1.0f : 0.0f);
    float e0b = f.z - ((i == c + 1) ? 1.0f : 0.0f);
    unsigned wa = ((unsigned)(unsigned short)bf16h(f.y - f.x) << 16) |
                  (unsigned)(unsigned short)bf16h(e0a);
    unsigned wb = ((unsigned)(unsigned short)bf16h(f.w - f.z) << 16) |
                  (unsigned)(unsigned short)bf16h(e0b);
    int idx = ((r * 2 + h2) * 64 + 16 * q + col16) * 4 + j;
    *(uint2*)(dst + idx) = make_uint2(wa, wb);
  }
}

// ---------------------------------------------------------------------------
// K1 kchain: 1024 blocks x 512 thr. bid = b*8 + hside*4 + quarter (XCD swizzle:
// bid&7 = site-range id). Wave k (0..7) runs segment t = quarter*8+k
// (13/12 sites), then 3-level T-world LDS tree fold -> quarter product X,
// stored row-major at halfbuf[bid].
// ---------------------------------------------------------------------------
__global__ __launch_bounds__(512, 8) void kchain(const float* __restrict__ x,
                                                 const unsigned* __restrict__ core2b,
                                                 float* __restrict__ halfbuf) {
  const int tid = threadIdx.x;
  const int lane = tid & 63;
  const int k = tid >> 6;  // wave 0..7
  const int col16 = lane & 15;
  const int q = lane >> 4;

  const int bid = blockIdx.x;       // 0..1023
  const int b = bid >> 3;           // batch 0..127
  const int hside = (bid >> 2) & 1; // half of the 784-site chain
  const int quarter = bid & 3;      // quarter of this 392-site chain

  const int t = quarter * 8 + k;  // segment 0..31 within chain
  const int start = (t < 8) ? 13 * t : 104 + 12 * (t - 8);  // 8*13+24*12=392
  const int len = (t < 8) ? 13 : 12;
  const int s_lo = hside * 392 + start;
  const int s_hi = s_lo + len - 1;

  __shared__ float smX[8][32 * 36];  // padded row-major slots (stride 36)

  facc acc[2][2];
#pragma unroll
  for (int r = 0; r < 2; ++r)
#pragma unroll
    for (int c = 0; c < 2; ++c)
#pragma unroll
      for (int j = 0; j < 4; ++j)
        acc[r][c][j] = (16 * r + 4 * q + j == 16 * c + col16) ? 1.0f : 0.0f;

  const uint4* cp = (const uint4*)core2b;
  const float* xb = x + b * 784;

  // ---- segment site loop (r9-verified): acc = S_t (C/D layout) ----
  for (int s = s_hi; s >= s_lo; --s) {
    uint4 raw[4];  // frag f = r*2+h2
#pragma unroll
    for (int f = 0; f < 4; ++f) raw[f] = cp[(size_t)s * 256 + f * 64 + lane];
    const float xv = xb[s];

    // B = bf16(P_old) BEFORE accumulation (C/D layout == B layout, K=16)
    bfrag B[2][2];
#pragma unroll
    for (int h2 = 0; h2 < 2; ++h2)
#pragma unroll
      for (int c = 0; c < 2; ++c) B[h2][c] = pack4(acc[h2][c]);

    bfrag A[2][2];
#pragma unroll
    for (int r = 0; r < 2; ++r)
#pragma unroll
      for (int h2 = 0; h2 < 2; ++h2) {
        unsigned wd[4] = {raw[r * 2 + h2].x, raw[r * 2 + h2].y, raw[r * 2 + h2].z,
                          raw[r * 2 + h2].w};
        float e[4];
#pragma unroll
        for (int j = 0; j < 4; ++j) {
          float e0 = __uint_as_float(wd[j] << 16);
          float d = __uint_as_float(wd[j] & 0xFFFF0000u);
          e[j] = fmaf(xv, d, e0);
        }
        A[r][h2] = packf4(e[0], e[1], e[2], e[3]);
      }

#pragma unroll
    for (int r = 0; r < 2; ++r)
#pragma unroll
      for (int c = 0; c < 2; ++c) {
        acc[r][c] = MFMA16(A[r][0], B[0][c], acc[r][c]);
        acc[r][c] = MFMA16(A[r][1], B[1][c], acc[r][c]);
      }
  }

  // ---- publish T_k = S_t^T row-major (fragment-level transpose, f4 store) ----
#pragma unroll
  for (int r = 0; r < 2; ++r)
#pragma unroll
    for (int c = 0; c < 2; ++c)
      *(float4*)&smX[k][(16 * c + col16) * 36 + 16 * r + 4 * q] =
          make_float4(acc[r][c][0], acc[r][c][1], acc[r][c][2], acc[r][c][3]);
  __syncthreads();

  // consumer A-frag read of slot m gives A-frags of T_m (row-major source).
  facc a2[2][2];
#pragma unroll
  for (int r = 0; r < 2; ++r)
#pragma unroll
    for (int c = 0; c < 2; ++c)
#pragma unroll
      for (int j = 0; j < 4; ++j)
        a2[r][c][j] = (16 * r + 4 * q + j == 16 * c + col16) ? 1.0f : 0.0f;

  const int fo0 = (16 * 0 + col16) * 36 + 4 * q;
  const int fo1 = (16 * 1 + col16) * 36 + 4 * q;

  // L1: even waves fold pair (k, k+1): a2 = T_{k+1} * T_k
  if ((k & 1) == 0) {
    float4 av[2][2];
#pragma unroll
    for (int R = 0; R < 2; ++R)
#pragma unroll
      for (int H = 0; H < 2; ++H)
        av[R][H] = *(const float4*)&smX[k][(R ? fo1 : fo0) + 16 * H];
    fold_step(a2, av);  // = T_k
#pragma unroll
    for (int R = 0; R < 2; ++R)
#pragma unroll
      for (int H = 0; H < 2; ++H)
        av[R][H] = *(const float4*)&smX[k + 1][(R ? fo1 : fo0) + 16 * H];
    fold_step(a2, av);  // = T_{k+1} T_k
  }
  __syncthreads();
  // producers of L2: waves 2, 6 publish (T-world: row-major write)
  if (k == 2 || k == 6) {
#pragma unroll
    for (int r = 0; r < 2; ++r)
#pragma unroll
      for (int c = 0; c < 2; ++c)
#pragma unroll
        for (int j = 0; j < 4; ++j)
          smX[k][(16 * r + 4 * q + j) * 36 + 16 * c + col16] = a2[r][c][j];
  }
  __syncthreads();
  // L2: waves 0, 4 fold partner k+2
  if (k == 0 || k == 4) {
    float4 av[2][2];
#pragma unroll
    for (int R = 0; R < 2; ++R)
#pragma unroll
      for (int H = 0; H < 2; ++H)
        av[R][H] = *(const float4*)&smX[k + 2][(R ? fo1 : fo0) + 16 * H];
    fold_step(a2, av);  // = T_{k+3..k}
  }
  __syncthreads();
  // producer of L3: wave 4 publishes
  if (k == 4) {
#pragma unroll
    for (int r = 0; r < 2; ++r)
#pragma unroll
      for (int c = 0; c < 2; ++c)
#pragma unroll
        for (int j = 0; j < 4; ++j)
          smX[4][(16 * r + 4 * q + j) * 36 + 16 * c + col16] = a2[r][c][j];
  }
  __syncthreads();
  // L3: wave 0 folds slot 4 -> X = T_{q8+7}...T_{q8}; store row-major
  if (k == 0) {
    float4 av[2][2];
#pragma unroll
    for (int R = 0; R < 2; ++R)
#pragma unroll
      for (int H = 0; H < 2; ++H)
        av[R][H] = *(const float4*)&smX[4][(R ? fo1 : fo0) + 16 * H];
    fold_step(a2, av);
    float* rm = halfbuf + (size_t)bid * 1024;
#pragma unroll
    for (int r = 0; r < 2; ++r)
#pragma unroll
      for (int c = 0; c < 2; ++c)
#pragma unroll
        for (int j = 0; j < 4; ++j)
          rm[(16 * r + 4 * q + j) * 32 + 16 * c + col16] = a2[r][c][j];
  }
}

// ---------------------------------------------------------------------------
// K2 gfin: 128 blocks x 64 thr.
// H = Left^T * Right^T = (X_L3..X_L0)(X_R3..X_R0): ascending fold_steps over
// slots R0..R3 then L0..L3 (slot = b*8 + hside*4 + quarter). Label contract.
// ---------------------------------------------------------------------------
__global__ __launch_bounds__(64) void gfin(const float* __restrict__ halfbuf,
                                           const float* __restrict__ label,
                                           float* __restrict__ out) {
  const int lane = threadIdx.x;
  const int b = blockIdx.x;
  const int col16 = lane & 15;
  const int q = lane >> 4;

  __shared__ float smF[1024];

  facc acc[2][2];
#pragma unroll
  for (int r = 0; r < 2; ++r)
#pragma unroll
    for (int c = 0; c < 2; ++c)
#pragma unroll
      for (int j = 0; j < 4; ++j)
        acc[r][c][j] = (16 * r + 4 * q + j == 16 * c + col16) ? 1.0f : 0.0f;

  // fold order: R quarters 0..3 (hside=1), then L quarters 0..3 (hside=0)
#pragma unroll
  for (int m = 0; m < 8; ++m) {
    const int hs = (m < 4) ? 1 : 0;
    const int qu = m & 3;
    const float* rm = halfbuf + (size_t)(b * 8 + hs * 4 + qu) * 1024;
    float4 av[2][2];
#pragma unroll
    for (int R = 0; R < 2; ++R)
#pragma unroll
      for (int H = 0; H < 2; ++H)
        av[R][H] = *(const float4*)&rm[(16 * R + col16) * 32 + 16 * H + 4 * q];
    fold_step(acc, av);
  }

  // acc = H = F^T (C/D layout); smF[j*32+k] = H[j][k]; label[(j*32+k)*10+l]
#pragma unroll
  for (int r = 0; r < 2; ++r)
#pragma unroll
    for (int c = 0; c < 2; ++c)
#pragma unroll
      for (int j = 0; j < 4; ++j)
        smF[(16 * r + 4 * q + j) * 32 + 16 * c + col16] = acc[r][c][j];
  __syncthreads();

  float part[10];
#pragma unroll
  for (int l = 0; l < 10; ++l) part[l] = 0.0f;
#pragma unroll
  for (int u = 0; u < 16; ++u) {
    int e = lane + 64 * u;
    float v = smF[e];
    const float* lb = label + (size_t)e * 10;
#pragma unroll
    for (int l = 0; l < 10; ++l) part[l] += v * lb[l];
  }
#pragma unroll
  for (int l = 0; l < 10; ++l) {
#pragma unroll
    for (int o = 32; o > 0; o >>= 1) part[l] += __shfl_xor(part[l], o, 64);
  }
  if (lane == 0) {
#pragma unroll
    for (int l = 0; l < 10; ++l) out[b * 10 + l] = part[l];
  }
}

extern "C" void kernel_launch(void* const* d_in, const int* in_sizes, int n_in,
                              void* d_out, int out_size, void* d_ws, size_t ws_size,
                              hipStream_t stream) {
  const float* x = (const float*)d_in[0];      // (128, 784)
  const float* core = (const float*)d_in[1];   // (784, 32, 32, 2)
  const float* label = (const float*)d_in[2];  // (32, 32, 10)
  float* out = (float*)d_out;                  // (128, 10)

  unsigned* core2b = (unsigned*)d_ws;                 // 3.2 MB
  float* halfbuf = (float*)d_ws + CORE2B_DWORDS;      // 4 MB

  hipLaunchKernelGGL(xform_k, dim3(784), dim3(256), 0, stream, core, core2b);
  hipLaunchKernelGGL(kchain, dim3(1024), dim3(512), 0, stream, x, core2b, halfbuf);
  hipLaunchKernelGGL(gfin, dim3(128), dim3(64), 0, stream, halfbuf, label, out);
}